// Round 5
// baseline (627.632 us; speedup 1.0000x reference)
//
#include <hip/hip_runtime.h>
#include <math.h>

#define NB 2048
#define NC 64
#define NF 17
#define NCOL (NC * NF)   // 1088

// znorm pipeline geometry
#define ZPB 16                 // rows per partial block
#define ZNB (NB / ZPB)         // 128 partial blocks
#define WS_STATS_OFF 4096
#define WS_PART_OFF 16384
#define WS_FAST_BYTES (WS_PART_OFF + ZNB * NCOL * 8)   // 1,130,496

// Position of channel c in sorted(f'ch{i}_') order.
__device__ __constant__ int POS[64] = {
   0, 11, 22, 33, 44, 55, 60, 61, 62, 63,   // c = 0..9
   1,  2,  3,  4,  5,  6,  7,  8,  9, 10,   // c = 10..19
  12, 13, 14, 15, 16, 17, 18, 19, 20, 21,   // c = 20..29
  23, 24, 25, 26, 27, 28, 29, 30, 31, 32,   // c = 30..39
  34, 35, 36, 37, 38, 39, 40, 41, 42, 43,   // c = 40..49
  45, 46, 47, 48, 49, 50, 51, 52, 53, 54,   // c = 50..59
  56, 57, 58, 59                             // c = 60..63
};

__global__ void init_tables(float* __restrict__ win, float2* __restrict__ tw) {
    int t = threadIdx.x;  // 256 threads
    double ang = (2.0 * 3.14159265358979323846 / 256.0) * (double)t;
    double cv = cos(ang), sv = sin(ang);
    win[t] = (float)(0.5 - 0.5 * cv);
    tw[t] = make_float2((float)cv, (float)sv);
}

// ============================================================================
// Kernel A: time-domain moments + histogram entropy (6 of 17 features).
// Slim: no tables, no DFT scratch -> low VGPR, 8 waves/SIMD target.
// All arithmetic sequences are verbatim from the validated fused kernel
// (bit-identical features).
// ============================================================================
__global__ __launch_bounds__(256) void mom_kernel(
    const float* __restrict__ x, float* __restrict__ out)
{
    // 4 copies per wave to cut same-address atomic serialization 4x.
    __shared__ unsigned histS[4][40];

    const int t = threadIdx.x;
    const int wid = t >> 6, l = t & 63;
    const int bc = (blockIdx.x << 2) + wid;
    unsigned* hist = histS[wid];

    // ---- load: lane holds x[8l .. 8l+7] ----
    const float4* xp4 = reinterpret_cast<const float4*>(x + (size_t)bc * 512);
    const float4 xa = xp4[2 * l], xb = xp4[2 * l + 1];
    float xe[8] = {xa.x, xa.y, xa.z, xa.w, xb.x, xb.y, xb.z, xb.w};

    // ---- pass 1: sums, min, max (group sums preserve exact mean order) ----
    float psum = 0.f, s2 = 0.f, mn = xe[0], mx = xe[0];
#pragma unroll
    for (int e = 0; e < 8; e++) {
        psum += xe[e];
        s2 = fmaf(xe[e], xe[e], s2);
        mn = fminf(mn, xe[e]);
        mx = fmaxf(mx, xe[e]);
    }
    float g = psum;
#pragma unroll
    for (int m = 1; m < 16; m <<= 1) g += __shfl_xor(g, m, 64);
    const float g0 = __shfl(g, 0, 64), g1 = __shfl(g, 16, 64),
                g2 = __shfl(g, 32, 64), g3 = __shfl(g, 48, 64);
    const float S1 = (g0 + g1) + (g2 + g3);
#pragma unroll
    for (int m = 1; m < 64; m <<= 1) {
        s2 += __shfl_xor(s2, m, 64);
        mn = fminf(mn, __shfl_xor(mn, m, 64));
        mx = fmaxf(mx, __shfl_xor(mx, m, 64));
    }
    const float mean = S1 * (1.0f / 512.0f);

    // ---- pass 2: centered moments ----
    float c2 = 0.f, c3 = 0.f, c4 = 0.f;
#pragma unroll
    for (int e = 0; e < 8; e++) {
        float a = xe[e] - mean;
        float a2 = a * a;
        c2 += a2;
        c3 = fmaf(a2, a, c3);
        c4 = fmaf(a2, a2, c4);
    }
#pragma unroll
    for (int m = 1; m < 64; m <<= 1) {
        c2 += __shfl_xor(c2, m, 64);
        c3 += __shfl_xor(c3, m, 64);
        c4 += __shfl_xor(c4, m, 64);
    }
    const float m2 = c2 * (1.0f / 512.0f);
    const float m3 = c3 * (1.0f / 512.0f);
    const float m4 = c4 * (1.0f / 512.0f);
    const float stdv = sqrtf(m2);
    const float skew = m3 / (m2 * stdv);
    const float kurt = m4 / (m2 * m2) - 3.0f;
    const float rms = sqrtf(s2 * (1.0f / 512.0f));

    // ---- histogram (bit-exact fp32: sub, IEEE div, mul, trunc) ----
    if (l < 40) hist[l] = 0u;
    {
        float wdt = mx - mn;
        float safew = (wdt > 0.0f) ? wdt : 1.0f;
        const int cpy = l & 3;
#pragma unroll
        for (int e = 0; e < 8; e++) {
            int bi = (int)((xe[e] - mn) / safew * 10.0f);
            bi = bi < 0 ? 0 : (bi > 9 ? 9 : bi);
            atomicAdd(&hist[bi * 4 + cpy], 1u);
        }
    }
    float entterm;
    {
        float cnt = 0.0f;
        if (l < 10) {
            unsigned cc = hist[4 * l] + hist[4 * l + 1] + hist[4 * l + 2] + hist[4 * l + 3];
            cnt = (float)cc;
        }
        float p = cnt * (1.0f / 512.0f);
        entterm = (p > 0.0f) ? p * logf(p) : 0.0f;
#pragma unroll
        for (int m = 1; m < 16; m <<= 1) entterm += __shfl_xor(entterm, m, 64);
    }
    const float ent = -entterm;

    // features owned by this kernel: 6 entropy, 9 kurtosis, 10 mean,
    // 12 rms, 13 skew, 14 std
    if (l == 6 || l == 9 || l == 10 || l == 12 || l == 13 || l == 14) {
        const int b = bc >> 6, c = bc & 63;
        float fv =
            (l == 6)  ? ent :
            (l == 9)  ? kurt :
            (l == 10) ? mean :
            (l == 12) ? rms :
            (l == 13) ? skew : stdv;
        out[(size_t)b * NCOL + POS[c] * NF + l] = fv;
    }
}

// ============================================================================
// Kernel B: Welch PSD (3 segs, 256-pt DFT) + band powers + peak freq
// (11 of 17 features). Twiddle loads de-hoisted into the segment loop to
// minimize live VGPRs.
// ============================================================================
template <bool HAS_TAB>
__global__ __launch_bounds__(256) void psd_kernel(
    const float* __restrict__ x,
    const float* __restrict__ gwin, const float2* __restrict__ gtw,
    float* __restrict__ out)
{
    __shared__ __align__(16) float winS[256];
    __shared__ float2 twS[256];      // (cos, sin) of 2*pi*m/256
    __shared__ float2 tw16S[16];     // (cos, sin) of 2*pi*m/16
    // per-wave scratch: vseg[256] floats + T[16][18] float2 (= 576 floats)
    __shared__ __align__(16) float wmem[4 * 832];

    const int t = threadIdx.x;
    const int wid = t >> 6, l = t & 63;
    const int bc = (blockIdx.x << 2) + wid;

    if (HAS_TAB) {
        winS[t] = gwin[t];
        twS[t] = gtw[t];
        if (t < 16) tw16S[t] = gtw[t << 4];
    } else {
        float ang = (float)t * (6.28318530717958647692f / 256.0f);
        float sv, cv;
        sincosf(ang, &sv, &cv);
        winS[t] = 0.5f - 0.5f * cv;
        twS[t] = make_float2(cv, sv);
        if (t < 16) {
            float a2 = (float)t * (6.28318530717958647692f / 16.0f);
            float s2v, c2v; sincosf(a2, &s2v, &c2v);
            tw16S[t] = make_float2(c2v, s2v);
        }
    }
    __syncthreads();

    float* vseg = &wmem[wid * 832];
    float2* T = reinterpret_cast<float2*>(&wmem[wid * 832 + 256]);

    // ---- load: lane holds x[8l .. 8l+7] ----
    const float4* xp4 = reinterpret_cast<const float4*>(x + (size_t)bc * 512);
    const float4 xa = xp4[2 * l], xb = xp4[2 * l + 1];
    float xe[8] = {xa.x, xa.y, xa.z, xa.w, xb.x, xb.y, xb.z, xb.w};

    // ---- 16-lane group sums (exact same op order as the fused kernel) ----
    float g = 0.f;
#pragma unroll
    for (int e = 0; e < 8; e++) g += xe[e];
#pragma unroll
    for (int m = 1; m < 16; m <<= 1) g += __shfl_xor(g, m, 64);
    const float g0 = __shfl(g, 0, 64), g1 = __shfl(g, 16, 64),
                g2 = __shfl(g, 32, 64), g3 = __shfl(g, 48, 64);

    const int rb = l >> 4, n0 = l & 15;
    // (-i)^((rb*a)&3) coefficients, a=0..3 (runtime rb -> +-1/0 floats)
    float car[4], cai[4];
#pragma unroll
    for (int a = 0; a < 4; a++) {
        int mm = (rb * a) & 3;
        car[a] = (mm == 0) ? 1.f : ((mm == 2) ? -1.f : 0.f);
        cai[a] = (mm == 1) ? -1.f : ((mm == 3) ? 1.f : 0.f);
    }

    // ---- Welch PSD: 3 segments, 256-pt DFT = (4x4) x (4x4) radix ----
    float P1 = 0.f, P2 = 0.f, P128 = 0.f;
#pragma unroll
    for (int s = 0; s < 3; s++) {
        const float smean =
            ((s == 0) ? (g0 + g1) : (s == 1) ? (g1 + g2) : (g2 + g3)) * (1.0f / 256.0f);
        const int D = l - 16 * s;   // active lanes hold 8 consecutive samples
        float alt = 0.f;
        if (D >= 0 && D < 32) {
            const float4 wA = reinterpret_cast<const float4*>(winS)[2 * D];
            const float4 wB = reinterpret_cast<const float4*>(winS)[2 * D + 1];
            float wv0 = wA.x * (xe[0] - smean);
            float wv1 = wA.y * (xe[1] - smean);
            float wv2 = wA.z * (xe[2] - smean);
            float wv3 = wA.w * (xe[3] - smean);
            float wv4 = wB.x * (xe[4] - smean);
            float wv5 = wB.y * (xe[5] - smean);
            float wv6 = wB.z * (xe[6] - smean);
            float wv7 = wB.w * (xe[7] - smean);
            reinterpret_cast<float4*>(vseg)[2 * D] = make_float4(wv0, wv1, wv2, wv3);
            reinterpret_cast<float4*>(vseg)[2 * D + 1] = make_float4(wv4, wv5, wv6, wv7);
            alt = ((wv0 - wv1) + (wv2 - wv3)) + ((wv4 - wv5) + (wv6 - wv7));
        }
        // X_128 = sum (-1)^n v_n  (real)
#pragma unroll
        for (int m = 1; m < 64; m <<= 1) alt += __shfl_xor(alt, m, 64);
        P128 = fmaf(alt, alt, P128);

        // stage 1: T[r][n0] = sum_n1 v[16 n1 + n0] W16^(r n1), r = rb + 4j
        float Dre[4], Dim[4];
#pragma unroll
        for (int q = 0; q < 4; q++) {
            float dr = vseg[16 * q + n0], di = 0.f;   // a=0 coeff = 1
#pragma unroll
            for (int a = 1; a < 4; a++) {
                float vv = vseg[64 * a + 16 * q + n0];
                dr = fmaf(vv, car[a], dr);
                di = fmaf(vv, cai[a], di);
            }
            Dre[q] = dr; Dim[q] = di;
        }
        const float E0r = Dre[0], E0i = Dim[0];
        float2 tv;
        tv = tw16S[rb];
        const float E1r = Dre[1] * tv.x + Dim[1] * tv.y;
        const float E1i = -Dre[1] * tv.y + Dim[1] * tv.x;
        tv = tw16S[(2 * rb) & 15];
        const float E2r = Dre[2] * tv.x + Dim[2] * tv.y;
        const float E2i = -Dre[2] * tv.y + Dim[2] * tv.x;
        tv = tw16S[(3 * rb) & 15];
        const float E3r = Dre[3] * tv.x + Dim[3] * tv.y;
        const float E3i = -Dre[3] * tv.y + Dim[3] * tv.x;
        // T[rb+4j] = sum_q E_q * (-i)^(j q)   (compile-time sign/swap)
        T[(rb +  0) * 18 + n0] = make_float2((E0r + E1r) + (E2r + E3r),
                                             (E0i + E1i) + (E2i + E3i));
        T[(rb +  4) * 18 + n0] = make_float2((E0r + E1i) - (E2r + E3i),
                                             (E0i - E1r) + (E3r - E2i));
        T[(rb +  8) * 18 + n0] = make_float2((E0r - E1r) + (E2r - E3r),
                                             (E0i - E1i) + (E2i - E3i));
        T[(rb + 12) * 18 + n0] = make_float2((E0r - E1i) - (E2r - E3i),
                                             (E0i + E1r) - (E2i + E3r));

        // stage 2: k1 = l, k2 = l + 64 share row rr = l & 15
        // twiddle cur_a = W_256^{4 l a} read exactly from table (no recurrence)
        float G0r, G0i, G1r, G1i, G2r, G2i, G3r, G3i;
        {
            const float4 t01 = *reinterpret_cast<const float4*>(&T[n0 * 18 + 0]);
            const float4 t23 = *reinterpret_cast<const float4*>(&T[n0 * 18 + 2]);
            G0r = t01.x; G0i = t01.y; G1r = t01.z; G1i = t01.w;
            G2r = t23.x; G2i = t23.y; G3r = t23.z; G3i = t23.w;
        }
#pragma unroll
        for (int a = 1; a < 4; a++) {
            float2 cw = twS[(4 * l * a) & 255];
            const float cx = cw.x, cy = -cw.y;
            const float4 t01 = *reinterpret_cast<const float4*>(&T[n0 * 18 + 4 * a]);
            const float4 t23 = *reinterpret_cast<const float4*>(&T[n0 * 18 + 4 * a + 2]);
            G0r = fmaf(t01.x, cx, fmaf(-t01.y, cy, G0r));
            G0i = fmaf(t01.x, cy, fmaf( t01.y, cx, G0i));
            G1r = fmaf(t01.z, cx, fmaf(-t01.w, cy, G1r));
            G1i = fmaf(t01.z, cy, fmaf( t01.w, cx, G1i));
            G2r = fmaf(t23.x, cx, fmaf(-t23.y, cy, G2r));
            G2i = fmaf(t23.x, cy, fmaf( t23.y, cx, G2i));
            G3r = fmaf(t23.z, cx, fmaf(-t23.w, cy, G3r));
            G3i = fmaf(t23.z, cy, fmaf( t23.w, cx, G3i));
        }
        const float H0r = G0r, H0i = G0i;
        float2 w1 = twS[l], w2 = twS[(2 * l) & 255], w3 = twS[(3 * l) & 255];
        const float H1r = G1r * w1.x + G1i * w1.y, H1i = -G1r * w1.y + G1i * w1.x;
        const float H2r = G2r * w2.x + G2i * w2.y, H2i = -G2r * w2.y + G2i * w2.x;
        const float H3r = G3r * w3.x + G3i * w3.y, H3i = -G3r * w3.y + G3i * w3.x;
        const float X1r = (H0r + H1r) + (H2r + H3r);
        const float X1i = (H0i + H1i) + (H2i + H3i);
        const float X2r = (H0r + H1i) - (H2r + H3i);   // sum H_q (-i)^q
        const float X2i = (H0i - H1r) + (H3r - H2i);
        P1 = fmaf(X1r, X1r, fmaf(X1i, X1i, P1));
        P2 = fmaf(X2r, X2r, fmaf(X2i, X2i, P2));
    }

    const float scc = (1.0f / 12288.0f) * (1.0f / 3.0f);
    const float psd1 = P1 * ((l == 0) ? 1.0f : 2.0f) * scc;   // k = l
    const float psd2 = P2 * 2.0f * scc;                        // k = l + 64
    const float psd128 = P128 * scc;                           // k = 128

    // ---- bands (trapz, dx = 0.5) + argmax ----
    auto wt = [](int k, int lo, int hi) -> float {
        if (k < lo || k > hi) return 0.0f;
        return (k == lo || k == hi) ? 0.25f : 0.5f;
    };
    float tot, al, be, de, ga, th, bv; int bi_;
    {
        const int k = l; const float p = psd1;
        tot = wt(k, 0, 128) * p;
        al = wt(k, 16, 24) * p; be = wt(k, 24, 60) * p; de = wt(k, 1, 8) * p;
        ga = wt(k, 60, 90) * p; th = wt(k, 8, 16) * p;
        bv = p; bi_ = k;
    }
    {
        const int k = l + 64; const float p = psd2;   // 64..127: interior of total
        tot += 0.5f * p;
        ga += wt(k, 60, 90) * p;
        if (p > bv) { bv = p; bi_ = k; }
    }
    if (l == 0) {
        tot += 0.25f * psd128;
        if (psd128 > bv) { bv = psd128; bi_ = 128; }
    }
    // packed (value, 16384-k) u64 max == same tie-break as (ov>bv)||(ov==bv&&oi<bi)
    unsigned long long pk =
        ((unsigned long long)__float_as_uint(bv) << 32) | (unsigned)(16384 - bi_);
#pragma unroll
    for (int m = 1; m < 64; m <<= 1) {
        tot += __shfl_xor(tot, m, 64);
        al  += __shfl_xor(al, m, 64);
        be  += __shfl_xor(be, m, 64);
        de  += __shfl_xor(de, m, 64);
        ga  += __shfl_xor(ga, m, 64);
        th  += __shfl_xor(th, m, 64);
        unsigned long long op = __shfl_xor(pk, m, 64);
        pk = (op > pk) ? op : pk;
    }
    bi_ = 16384 - (int)(unsigned)(pk & 0xffffffffull);
    const bool ok = tot > 1e-6f;

    // features owned by this kernel: 0..5, 7, 8, 11, 15, 16
    if (l < NF && !(l == 6 || l == 9 || l == 10 || l == 12 || l == 13 || l == 14)) {
        const int b = bc >> 6, c = bc & 63;
        float fv =
            (l == 0)  ? al :
            (l == 1)  ? (ok ? al / tot : 0.f) :
            (l == 2)  ? be :
            (l == 3)  ? (ok ? be / tot : 0.f) :
            (l == 4)  ? de :
            (l == 5)  ? (ok ? de / tot : 0.f) :
            (l == 7)  ? ga :
            (l == 8)  ? (ok ? ga / tot : 0.f) :
            (l == 11) ? (0.5f * (float)bi_) :
            (l == 15) ? th : (ok ? th / tot : 0.f);
        out[(size_t)b * NCOL + POS[c] * NF + l] = fv;
    }
}

// ---------------- fast znorm pipeline (coalesced, 3 kernels) ----------------

__global__ __launch_bounds__(256) void zstat_partial(
    const float* __restrict__ fm, float2* __restrict__ part)
{
    const int blk = blockIdx.x;          // 0..ZNB-1
    const int row0 = blk * ZPB;
    for (int c = threadIdx.x; c < NCOL; c += 256) {
        float s = 0.f, ss = 0.f;
#pragma unroll
        for (int r = 0; r < ZPB; r++) {
            float v = fm[(size_t)(row0 + r) * NCOL + c];
            s += v;
            ss = fmaf(v, v, ss);
        }
        part[(size_t)blk * NCOL + c] = make_float2(s, ss);
    }
}

__global__ __launch_bounds__(256) void zstat_final(
    const float2* __restrict__ part, float2* __restrict__ stats)
{
    const int c = blockIdx.x * 256 + threadIdx.x;
    if (c >= NCOL) return;
    double s = 0.0, ss = 0.0;
    for (int b = 0; b < ZNB; b++) {
        float2 p = part[(size_t)b * NCOL + c];
        s += (double)p.x;
        ss += (double)p.y;
    }
    const double mu_d = s * (1.0 / 2048.0);
    double var_d = ss * (1.0 / 2048.0) - mu_d * mu_d;
    if (var_d < 0.0) var_d = 0.0;
    const float mu = (float)mu_d;
    const float sd = sqrtf((float)var_d);
    stats[c] = make_float2(mu, sd + 1e-6f);
}

__global__ __launch_bounds__(256) void zapply(
    float* __restrict__ fm, const float2* __restrict__ stats)
{
    const int row = blockIdx.x;          // 0..NB-1
    float4* p4 = reinterpret_cast<float4*>(fm + (size_t)row * NCOL);
    for (int i = threadIdx.x; i < NCOL / 4; i += 256) {
        float4 v = p4[i];
        const float2 s0 = stats[4 * i + 0];
        const float2 s1 = stats[4 * i + 1];
        const float2 s2 = stats[4 * i + 2];
        const float2 s3 = stats[4 * i + 3];
        v.x = (v.x - s0.x) / s0.y;
        v.y = (v.y - s1.x) / s1.y;
        v.z = (v.z - s2.x) / s2.y;
        v.w = (v.w - s3.x) / s3.y;
        p4[i] = v;
    }
}

// ---------------- fallback znorm (old, column-per-block) ----------------
__global__ __launch_bounds__(256) void znorm_kernel(float* __restrict__ fm) {
    __shared__ float red[4];
    const int col = blockIdx.x;    // 1088 columns
    const int t = threadIdx.x;
    const int wid = t >> 6, lane = t & 63;
    float v[8];
    float s = 0.0f;
#pragma unroll
    for (int i = 0; i < 8; i++) {
        v[i] = fm[(size_t)(i * 256 + t) * NCOL + col];
        s += v[i];
    }
#pragma unroll
    for (int off = 32; off; off >>= 1) s += __shfl_down(s, off, 64);
    if (lane == 0) red[wid] = s;
    __syncthreads();
    const float mu = (red[0] + red[1] + red[2] + red[3]) * (1.0f / 2048.0f);
    __syncthreads();
    float q = 0.0f;
#pragma unroll
    for (int i = 0; i < 8; i++) {
        float dd = v[i] - mu;
        q += dd * dd;
    }
#pragma unroll
    for (int off = 32; off; off >>= 1) q += __shfl_down(q, off, 64);
    if (lane == 0) red[wid] = q;
    __syncthreads();
    const float sd = sqrtf((red[0] + red[1] + red[2] + red[3]) * (1.0f / 2048.0f));
    const float den = sd + 1e-6f;
#pragma unroll
    for (int i = 0; i < 8; i++)
        fm[(size_t)(i * 256 + t) * NCOL + col] = (v[i] - mu) / den;
}

extern "C" void kernel_launch(void* const* d_in, const int* in_sizes, int n_in,
                              void* d_out, int out_size, void* d_ws, size_t ws_size,
                              hipStream_t stream) {
    const float* x = (const float*)d_in[0];
    float* out = (float*)d_out;
    const int nblocks = (NB * NC) / 4;   // one wave per channel, 4 waves/block

    const bool has_tab = (d_ws != nullptr && ws_size >= 4096);
    const bool fast_z = (d_ws != nullptr && ws_size >= (size_t)WS_FAST_BYTES);

    mom_kernel<<<nblocks, 256, 0, stream>>>(x, out);

    if (has_tab) {
        float* win = (float*)d_ws;
        float2* tw = (float2*)((char*)d_ws + 1024);
        init_tables<<<1, 256, 0, stream>>>(win, tw);
        psd_kernel<true><<<nblocks, 256, 0, stream>>>(x, win, tw, out);
    } else {
        psd_kernel<false><<<nblocks, 256, 0, stream>>>(x, nullptr, nullptr, out);
    }

    if (fast_z) {
        float2* stats = (float2*)((char*)d_ws + WS_STATS_OFF);
        float2* part = (float2*)((char*)d_ws + WS_PART_OFF);
        zstat_partial<<<ZNB, 256, 0, stream>>>(out, part);
        zstat_final<<<(NCOL + 255) / 256, 256, 0, stream>>>(part, stats);
        zapply<<<NB, 256, 0, stream>>>(out, stats);
    } else {
        znorm_kernel<<<NCOL, 256, 0, stream>>>(out);
    }
}

// Round 6
// 584.645 us; speedup vs baseline: 1.0735x; 1.0735x over previous
//
#include <hip/hip_runtime.h>
#include <math.h>

#define NB 2048
#define NC 64
#define NF 17
#define NCOL (NC * NF)   // 1088

// znorm pipeline geometry
#define ZPB 16                 // rows per partial block
#define ZNB (NB / ZPB)         // 128 partial blocks
#define WS_STATS_OFF 4096
#define WS_PART_OFF 16384
#define WS_FAST_BYTES (WS_PART_OFF + ZNB * NCOL * 8)   // 1,130,496

// Position of channel c in sorted(f'ch{i}_') order.
__device__ __constant__ int POS[64] = {
   0, 11, 22, 33, 44, 55, 60, 61, 62, 63,   // c = 0..9
   1,  2,  3,  4,  5,  6,  7,  8,  9, 10,   // c = 10..19
  12, 13, 14, 15, 16, 17, 18, 19, 20, 21,   // c = 20..29
  23, 24, 25, 26, 27, 28, 29, 30, 31, 32,   // c = 30..39
  34, 35, 36, 37, 38, 39, 40, 41, 42, 43,   // c = 40..49
  45, 46, 47, 48, 49, 50, 51, 52, 53, 54,   // c = 50..59
  56, 57, 58, 59                             // c = 60..63
};

__global__ void init_tables(float* __restrict__ win, float2* __restrict__ tw) {
    int t = threadIdx.x;  // 256 threads
    double ang = (2.0 * 3.14159265358979323846 / 256.0) * (double)t;
    double cv = cos(ang), sv = sin(ang);
    win[t] = (float)(0.5 - 0.5 * cv);
    tw[t] = make_float2((float)cv, (float)sv);
}

// constant-index float4 component (folds under #pragma unroll)
#define ELEM4(v, q) ((q) == 0 ? (v).x : (q) == 1 ? (v).y : (q) == 2 ? (v).z : (v).w)

// One wave (64 lanes) processes one (b,c) channel end-to-end (all 17 features).
// Key latency fixes vs previous rounds (all bit-identical arithmetic):
//  - alt (k=128 bin) reduces deferred to one 3-chain interleaved cluster
//  - s2/mn/mx merged with c2/c3/c4 into one 6-chain cluster
//  - entropy reduce folded into the final band/argmax cluster
//  - vsegT[16][20] transposed+padded layout: stage-1 reads are 4x ds_read_b128
template <bool HAS_TAB>
__global__ __launch_bounds__(256) void feat_kernel(
    const float* __restrict__ x,
    const float* __restrict__ gwin, const float2* __restrict__ gtw,
    float* __restrict__ out)
{
    __shared__ __align__(16) float winS[256];
    __shared__ float2 twS[256];      // (cos, sin) of 2*pi*m/256
    __shared__ float2 tw16S[16];     // (cos, sin) of 2*pi*m/16
    // per-wave scratch: vsegT[16][20] floats (320) + T[16][18] float2 (576 floats)
    __shared__ __align__(16) float wmem[4 * 896];
    // 4 copies per wave to cut same-address atomic serialization 4x.
    __shared__ unsigned histS[4][40];

    const int t = threadIdx.x;
    const int wid = t >> 6, l = t & 63;
    const int bc = (blockIdx.x << 2) + wid;

    if (HAS_TAB) {
        winS[t] = gwin[t];
        twS[t] = gtw[t];
        if (t < 16) tw16S[t] = gtw[t << 4];
    } else {
        float ang = (float)t * (6.28318530717958647692f / 256.0f);
        float sv, cv;
        sincosf(ang, &sv, &cv);
        winS[t] = 0.5f - 0.5f * cv;
        twS[t] = make_float2(cv, sv);
        if (t < 16) {
            float a2 = (float)t * (6.28318530717958647692f / 16.0f);
            float s2v, c2v; sincosf(a2, &s2v, &c2v);
            tw16S[t] = make_float2(c2v, s2v);
        }
    }
    __syncthreads();

    float* vsegT = &wmem[wid * 896];                                  // [16][20]
    float2* T = reinterpret_cast<float2*>(&wmem[wid * 896 + 320]);    // [16][18]
    unsigned* hist = histS[wid];

    // ---- load: lane holds x[8l .. 8l+7] ----
    const float4* xp4 = reinterpret_cast<const float4*>(x + (size_t)bc * 512);
    const float4 xa = xp4[2 * l], xb = xp4[2 * l + 1];
    float xe[8] = {xa.x, xa.y, xa.z, xa.w, xb.x, xb.y, xb.z, xb.w};

    // ---- pass 1: per-lane sums, min, max ----
    float psum = 0.f, s2 = 0.f, mn = xe[0], mx = xe[0];
#pragma unroll
    for (int e = 0; e < 8; e++) {
        psum += xe[e];
        s2 = fmaf(xe[e], xe[e], s2);
        mn = fminf(mn, xe[e]);
        mx = fmaxf(mx, xe[e]);
    }
    float g = psum;
#pragma unroll
    for (int m = 1; m < 16; m <<= 1) g += __shfl_xor(g, m, 64);
    const float g0 = __shfl(g, 0, 64), g1 = __shfl(g, 16, 64),
                g2 = __shfl(g, 32, 64), g3 = __shfl(g, 48, 64);
    const float S1 = (g0 + g1) + (g2 + g3);
    const float mean = S1 * (1.0f / 512.0f);

    // ---- pass 2: per-lane centered moments ----
    float c2 = 0.f, c3 = 0.f, c4 = 0.f;
#pragma unroll
    for (int e = 0; e < 8; e++) {
        float a = xe[e] - mean;
        float a2 = a * a;
        c2 += a2;
        c3 = fmaf(a2, a, c3);
        c4 = fmaf(a2, a2, c4);
    }
    // ---- merged 6-chain butterfly (each quantity's mask sequence unchanged) ----
#pragma unroll
    for (int m = 1; m < 64; m <<= 1) {
        s2 += __shfl_xor(s2, m, 64);
        mn = fminf(mn, __shfl_xor(mn, m, 64));
        mx = fmaxf(mx, __shfl_xor(mx, m, 64));
        c2 += __shfl_xor(c2, m, 64);
        c3 += __shfl_xor(c3, m, 64);
        c4 += __shfl_xor(c4, m, 64);
    }
    const float m2 = c2 * (1.0f / 512.0f);
    const float m3 = c3 * (1.0f / 512.0f);
    const float m4 = c4 * (1.0f / 512.0f);
    const float stdv = sqrtf(m2);
    const float skew = m3 / (m2 * stdv);
    const float kurt = m4 / (m2 * m2) - 3.0f;
    const float rms = sqrtf(s2 * (1.0f / 512.0f));

    // ---- histogram (bit-exact fp32: sub, IEEE div, mul, trunc) ----
    if (l < 40) hist[l] = 0u;
    {
        float wdt = mx - mn;
        float safew = (wdt > 0.0f) ? wdt : 1.0f;
        const int cpy = l & 3;
#pragma unroll
        for (int e = 0; e < 8; e++) {
            int bi = (int)((xe[e] - mn) / safew * 10.0f);
            bi = bi < 0 ? 0 : (bi > 9 ? 9 : bi);
            atomicAdd(&hist[bi * 4 + cpy], 1u);
        }
    }
    float entterm;   // per-lane term; reduce deferred to the final cluster
    {
        float cnt = 0.0f;
        if (l < 10) {
            unsigned cc = hist[4 * l] + hist[4 * l + 1] + hist[4 * l + 2] + hist[4 * l + 3];
            cnt = (float)cc;
        }
        float p = cnt * (1.0f / 512.0f);
        entterm = (p > 0.0f) ? p * logf(p) : 0.0f;
    }

    // ---- stage-1 coefficients: (-i)^((rb*a)&3), a=0..3 ----
    const int rb = l >> 4, n0 = l & 15;
    float car[4], cai[4];
#pragma unroll
    for (int a = 0; a < 4; a++) {
        int mm = (rb * a) & 3;
        car[a] = (mm == 0) ? 1.f : ((mm == 2) ? -1.f : 0.f);
        cai[a] = (mm == 1) ? -1.f : ((mm == 3) ? 1.f : 0.f);
    }

    // ---- Welch PSD: 3 segments, 256-pt DFT = (4x4) x (4x4) radix ----
    float P1 = 0.f, P2 = 0.f;
    float alt0 = 0.f, alt1 = 0.f, alt2 = 0.f;   // deferred k=128 partials
#pragma unroll
    for (int s = 0; s < 3; s++) {
        const float smean =
            ((s == 0) ? (g0 + g1) : (s == 1) ? (g1 + g2) : (g2 + g3)) * (1.0f / 256.0f);
        const int D = l - 16 * s;   // active lanes hold 8 consecutive samples
        if (D >= 0 && D < 32) {
            const float4 wA = reinterpret_cast<const float4*>(winS)[2 * D];
            const float4 wB = reinterpret_cast<const float4*>(winS)[2 * D + 1];
            float wv0 = wA.x * (xe[0] - smean);
            float wv1 = wA.y * (xe[1] - smean);
            float wv2 = wA.z * (xe[2] - smean);
            float wv3 = wA.w * (xe[3] - smean);
            float wv4 = wB.x * (xe[4] - smean);
            float wv5 = wB.y * (xe[5] - smean);
            float wv6 = wB.z * (xe[6] - smean);
            float wv7 = wB.w * (xe[7] - smean);
            // transposed store: sample n=8D+e -> vsegT[(n&15)*20 + (n>>4)]
            float* vt = vsegT + ((D & 1) << 3) * 20 + (D >> 1);
            vt[0 * 20] = wv0; vt[1 * 20] = wv1; vt[2 * 20] = wv2; vt[3 * 20] = wv3;
            vt[4 * 20] = wv4; vt[5 * 20] = wv5; vt[6 * 20] = wv6; vt[7 * 20] = wv7;
            float alt = ((wv0 - wv1) + (wv2 - wv3)) + ((wv4 - wv5) + (wv6 - wv7));
            if (s == 0) alt0 = alt; else if (s == 1) alt1 = alt; else alt2 = alt;
        }

        // stage 1: T[r][n0] = sum_n1 v[16 n1 + n0] W16^(r n1), r = rb + 4j
        // v[n1] = vsegT[n0*20 + n1]: 4x conflict-free ds_read_b128
        const float4 r0 = *reinterpret_cast<const float4*>(&vsegT[n0 * 20 + 0]);
        const float4 r1 = *reinterpret_cast<const float4*>(&vsegT[n0 * 20 + 4]);
        const float4 r2 = *reinterpret_cast<const float4*>(&vsegT[n0 * 20 + 8]);
        const float4 r3 = *reinterpret_cast<const float4*>(&vsegT[n0 * 20 + 12]);
        float Dre[4], Dim[4];
#pragma unroll
        for (int q = 0; q < 4; q++) {
            float dr = ELEM4(r0, q), di = 0.f;   // a=0 coeff = 1; v[4a+q]=r_a[q]
            dr = fmaf(ELEM4(r1, q), car[1], dr); di = fmaf(ELEM4(r1, q), cai[1], di);
            dr = fmaf(ELEM4(r2, q), car[2], dr); di = fmaf(ELEM4(r2, q), cai[2], di);
            dr = fmaf(ELEM4(r3, q), car[3], dr); di = fmaf(ELEM4(r3, q), cai[3], di);
            Dre[q] = dr; Dim[q] = di;
        }
        const float E0r = Dre[0], E0i = Dim[0];
        float2 tv;
        tv = tw16S[rb];
        const float E1r = Dre[1] * tv.x + Dim[1] * tv.y;
        const float E1i = -Dre[1] * tv.y + Dim[1] * tv.x;
        tv = tw16S[(2 * rb) & 15];
        const float E2r = Dre[2] * tv.x + Dim[2] * tv.y;
        const float E2i = -Dre[2] * tv.y + Dim[2] * tv.x;
        tv = tw16S[(3 * rb) & 15];
        const float E3r = Dre[3] * tv.x + Dim[3] * tv.y;
        const float E3i = -Dre[3] * tv.y + Dim[3] * tv.x;
        // T[rb+4j] = sum_q E_q * (-i)^(j q)   (compile-time sign/swap)
        T[(rb +  0) * 18 + n0] = make_float2((E0r + E1r) + (E2r + E3r),
                                             (E0i + E1i) + (E2i + E3i));
        T[(rb +  4) * 18 + n0] = make_float2((E0r + E1i) - (E2r + E3i),
                                             (E0i - E1r) + (E3r - E2i));
        T[(rb +  8) * 18 + n0] = make_float2((E0r - E1r) + (E2r - E3r),
                                             (E0i - E1i) + (E2i - E3i));
        T[(rb + 12) * 18 + n0] = make_float2((E0r - E1i) - (E2r - E3i),
                                             (E0i + E1r) - (E2i + E3r));

        // stage 2: k1 = l, k2 = l + 64 share row n0 = l & 15
        float G0r, G0i, G1r, G1i, G2r, G2i, G3r, G3i;
        {
            const float4 t01 = *reinterpret_cast<const float4*>(&T[n0 * 18 + 0]);
            const float4 t23 = *reinterpret_cast<const float4*>(&T[n0 * 18 + 2]);
            G0r = t01.x; G0i = t01.y; G1r = t01.z; G1i = t01.w;
            G2r = t23.x; G2i = t23.y; G3r = t23.z; G3i = t23.w;
        }
#pragma unroll
        for (int a = 1; a < 4; a++) {
            float2 cw = twS[(4 * l * a) & 255];
            const float cx = cw.x, cy = -cw.y;
            const float4 t01 = *reinterpret_cast<const float4*>(&T[n0 * 18 + 4 * a]);
            const float4 t23 = *reinterpret_cast<const float4*>(&T[n0 * 18 + 4 * a + 2]);
            G0r = fmaf(t01.x, cx, fmaf(-t01.y, cy, G0r));
            G0i = fmaf(t01.x, cy, fmaf( t01.y, cx, G0i));
            G1r = fmaf(t01.z, cx, fmaf(-t01.w, cy, G1r));
            G1i = fmaf(t01.z, cy, fmaf( t01.w, cx, G1i));
            G2r = fmaf(t23.x, cx, fmaf(-t23.y, cy, G2r));
            G2i = fmaf(t23.x, cy, fmaf( t23.y, cx, G2i));
            G3r = fmaf(t23.z, cx, fmaf(-t23.w, cy, G3r));
            G3i = fmaf(t23.z, cy, fmaf( t23.w, cx, G3i));
        }
        const float H0r = G0r, H0i = G0i;
        float2 w1 = twS[l], w2 = twS[(2 * l) & 255], w3 = twS[(3 * l) & 255];
        const float H1r = G1r * w1.x + G1i * w1.y, H1i = -G1r * w1.y + G1i * w1.x;
        const float H2r = G2r * w2.x + G2i * w2.y, H2i = -G2r * w2.y + G2i * w2.x;
        const float H3r = G3r * w3.x + G3i * w3.y, H3i = -G3r * w3.y + G3i * w3.x;
        const float X1r = (H0r + H1r) + (H2r + H3r);
        const float X1i = (H0i + H1i) + (H2i + H3i);
        const float X2r = (H0r + H1i) - (H2r + H3i);   // sum H_q (-i)^q
        const float X2i = (H0i - H1r) + (H3r - H2i);
        P1 = fmaf(X1r, X1r, fmaf(X1i, X1i, P1));
        P2 = fmaf(X2r, X2r, fmaf(X2i, X2i, P2));
    }

    // ---- deferred alt reduces: 3 interleaved chains (same masks per chain) ----
#pragma unroll
    for (int m = 1; m < 64; m <<= 1) {
        alt0 += __shfl_xor(alt0, m, 64);
        alt1 += __shfl_xor(alt1, m, 64);
        alt2 += __shfl_xor(alt2, m, 64);
    }
    float P128 = fmaf(alt0, alt0, 0.0f);
    P128 = fmaf(alt1, alt1, P128);
    P128 = fmaf(alt2, alt2, P128);

    const float scc = (1.0f / 12288.0f) * (1.0f / 3.0f);
    const float psd1 = P1 * ((l == 0) ? 1.0f : 2.0f) * scc;   // k = l
    const float psd2 = P2 * 2.0f * scc;                        // k = l + 64
    const float psd128 = P128 * scc;                           // k = 128

    // ---- bands (trapz, dx = 0.5) + argmax ----
    auto wt = [](int k, int lo, int hi) -> float {
        if (k < lo || k > hi) return 0.0f;
        return (k == lo || k == hi) ? 0.25f : 0.5f;
    };
    float tot, al, be, de, ga, th, bv; int bi_;
    {
        const int k = l; const float p = psd1;
        tot = wt(k, 0, 128) * p;
        al = wt(k, 16, 24) * p; be = wt(k, 24, 60) * p; de = wt(k, 1, 8) * p;
        ga = wt(k, 60, 90) * p; th = wt(k, 8, 16) * p;
        bv = p; bi_ = k;
    }
    {
        const int k = l + 64; const float p = psd2;   // 64..127: interior of total
        tot += 0.5f * p;
        ga += wt(k, 60, 90) * p;
        if (p > bv) { bv = p; bi_ = k; }
    }
    if (l == 0) {
        tot += 0.25f * psd128;
        if (psd128 > bv) { bv = psd128; bi_ = 128; }
    }
    // packed (value, 16384-k) u64 max == same tie-break as (ov>bv)||(ov==bv&&oi<bi)
    unsigned long long pk =
        ((unsigned long long)__float_as_uint(bv) << 32) | (unsigned)(16384 - bi_);
    // ---- final cluster: 6 sums + u64 max + entropy (masks 1..8) interleaved ----
#pragma unroll
    for (int m = 1; m < 64; m <<= 1) {
        tot += __shfl_xor(tot, m, 64);
        al  += __shfl_xor(al, m, 64);
        be  += __shfl_xor(be, m, 64);
        de  += __shfl_xor(de, m, 64);
        ga  += __shfl_xor(ga, m, 64);
        th  += __shfl_xor(th, m, 64);
        unsigned long long op = __shfl_xor(pk, m, 64);
        pk = (op > pk) ? op : pk;
        if (m < 16) entterm += __shfl_xor(entterm, m, 64);
    }
    const float ent = -entterm;   // valid on lanes 0..15 (lane 6 uses it)
    bi_ = 16384 - (int)(unsigned)(pk & 0xffffffffull);
    const bool ok = tot > 1e-6f;
    const float alR = ok ? al / tot : 0.f;
    const float beR = ok ? be / tot : 0.f;
    const float deR = ok ? de / tot : 0.f;
    const float gaR = ok ? ga / tot : 0.f;
    const float thR = ok ? th / tot : 0.f;
    const float pkf = 0.5f * (float)bi_;

    if (l < NF) {
        const int b = bc >> 6, c = bc & 63;
        float fv =
            (l == 0)  ? al :
            (l == 1)  ? alR :
            (l == 2)  ? be :
            (l == 3)  ? beR :
            (l == 4)  ? de :
            (l == 5)  ? deR :
            (l == 6)  ? ent :
            (l == 7)  ? ga :
            (l == 8)  ? gaR :
            (l == 9)  ? kurt :
            (l == 10) ? mean :
            (l == 11) ? pkf :
            (l == 12) ? rms :
            (l == 13) ? skew :
            (l == 14) ? stdv :
            (l == 15) ? th : thR;
        out[(size_t)b * NCOL + POS[c] * NF + l] = fv;
    }
}

// ---------------- fast znorm pipeline (coalesced, 3 kernels) ----------------

__global__ __launch_bounds__(256) void zstat_partial(
    const float* __restrict__ fm, float2* __restrict__ part)
{
    const int blk = blockIdx.x;          // 0..ZNB-1
    const int row0 = blk * ZPB;
    for (int c = threadIdx.x; c < NCOL; c += 256) {
        float s = 0.f, ss = 0.f;
#pragma unroll
        for (int r = 0; r < ZPB; r++) {
            float v = fm[(size_t)(row0 + r) * NCOL + c];
            s += v;
            ss = fmaf(v, v, ss);
        }
        part[(size_t)blk * NCOL + c] = make_float2(s, ss);
    }
}

__global__ __launch_bounds__(256) void zstat_final(
    const float2* __restrict__ part, float2* __restrict__ stats)
{
    const int c = blockIdx.x * 256 + threadIdx.x;
    if (c >= NCOL) return;
    double s = 0.0, ss = 0.0;
    for (int b = 0; b < ZNB; b++) {
        float2 p = part[(size_t)b * NCOL + c];
        s += (double)p.x;
        ss += (double)p.y;
    }
    const double mu_d = s * (1.0 / 2048.0);
    double var_d = ss * (1.0 / 2048.0) - mu_d * mu_d;
    if (var_d < 0.0) var_d = 0.0;
    const float mu = (float)mu_d;
    const float sd = sqrtf((float)var_d);
    stats[c] = make_float2(mu, sd + 1e-6f);
}

__global__ __launch_bounds__(256) void zapply(
    float* __restrict__ fm, const float2* __restrict__ stats)
{
    const int row = blockIdx.x;          // 0..NB-1
    float4* p4 = reinterpret_cast<float4*>(fm + (size_t)row * NCOL);
    for (int i = threadIdx.x; i < NCOL / 4; i += 256) {
        float4 v = p4[i];
        const float2 s0 = stats[4 * i + 0];
        const float2 s1 = stats[4 * i + 1];
        const float2 s2 = stats[4 * i + 2];
        const float2 s3 = stats[4 * i + 3];
        v.x = (v.x - s0.x) / s0.y;
        v.y = (v.y - s1.x) / s1.y;
        v.z = (v.z - s2.x) / s2.y;
        v.w = (v.w - s3.x) / s3.y;
        p4[i] = v;
    }
}

// ---------------- fallback znorm (old, column-per-block) ----------------
__global__ __launch_bounds__(256) void znorm_kernel(float* __restrict__ fm) {
    __shared__ float red[4];
    const int col = blockIdx.x;    // 1088 columns
    const int t = threadIdx.x;
    const int wid = t >> 6, lane = t & 63;
    float v[8];
    float s = 0.0f;
#pragma unroll
    for (int i = 0; i < 8; i++) {
        v[i] = fm[(size_t)(i * 256 + t) * NCOL + col];
        s += v[i];
    }
#pragma unroll
    for (int off = 32; off; off >>= 1) s += __shfl_down(s, off, 64);
    if (lane == 0) red[wid] = s;
    __syncthreads();
    const float mu = (red[0] + red[1] + red[2] + red[3]) * (1.0f / 2048.0f);
    __syncthreads();
    float q = 0.0f;
#pragma unroll
    for (int i = 0; i < 8; i++) {
        float dd = v[i] - mu;
        q += dd * dd;
    }
#pragma unroll
    for (int off = 32; off; off >>= 1) q += __shfl_down(q, off, 64);
    if (lane == 0) red[wid] = q;
    __syncthreads();
    const float sd = sqrtf((red[0] + red[1] + red[2] + red[3]) * (1.0f / 2048.0f));
    const float den = sd + 1e-6f;
#pragma unroll
    for (int i = 0; i < 8; i++)
        fm[(size_t)(i * 256 + t) * NCOL + col] = (v[i] - mu) / den;
}

extern "C" void kernel_launch(void* const* d_in, const int* in_sizes, int n_in,
                              void* d_out, int out_size, void* d_ws, size_t ws_size,
                              hipStream_t stream) {
    const float* x = (const float*)d_in[0];
    float* out = (float*)d_out;
    const int nblocks = (NB * NC) / 4;   // one wave per channel, 4 waves/block

    const bool has_tab = (d_ws != nullptr && ws_size >= 4096);
    const bool fast_z = (d_ws != nullptr && ws_size >= (size_t)WS_FAST_BYTES);

    if (has_tab) {
        float* win = (float*)d_ws;
        float2* tw = (float2*)((char*)d_ws + 1024);
        init_tables<<<1, 256, 0, stream>>>(win, tw);
        feat_kernel<true><<<nblocks, 256, 0, stream>>>(x, win, tw, out);
    } else {
        feat_kernel<false><<<nblocks, 256, 0, stream>>>(x, nullptr, nullptr, out);
    }

    if (fast_z) {
        float2* stats = (float2*)((char*)d_ws + WS_STATS_OFF);
        float2* part = (float2*)((char*)d_ws + WS_PART_OFF);
        zstat_partial<<<ZNB, 256, 0, stream>>>(out, part);
        zstat_final<<<(NCOL + 255) / 256, 256, 0, stream>>>(part, stats);
        zapply<<<NB, 256, 0, stream>>>(out, stats);
    } else {
        znorm_kernel<<<NCOL, 256, 0, stream>>>(out);
    }
}